// Round 1
// baseline (543.269 us; speedup 1.0000x reference)
//
#include <hip/hip_runtime.h>

// ============================================================================
// Fused 2-layer transformer encoder (B=1024, T=128, D=128, H=8, HD=16, FF=512)
// One workgroup per batch element; all activations resident in LDS across
// both layers; bf16 MFMA (16x16x32) for every matmul; fp32 accumulation,
// softmax and layernorm in fp32.
// ============================================================================

typedef __attribute__((ext_vector_type(8))) __bf16 bf16x8;
typedef __attribute__((ext_vector_type(4))) float fx4;

#define MFMA16(a, b, c) __builtin_amdgcn_mfma_f32_16x16x32_bf16((a), (b), (c), 0, 0, 0)

// LDS strides (elements). All ≡ 0 mod 8 (16B-aligned rows) and chosen so the
// dword stride ≡ 2 or 4 mod 32 -> worst-case 2-way bank aliasing (free).
#define XS_S 136
#define QK_S 264
#define VT_S 136
#define PS_S 72

static __device__ __forceinline__ unsigned short f2bf(float f) {
    __bf16 b = (__bf16)f;                       // fptrunc f32->bf16, RTN-even
    return __builtin_bit_cast(unsigned short, b);
}
static __device__ __forceinline__ float bf2f(unsigned short u) {
    return (float)__builtin_bit_cast(__bf16, u);
}

// --------------------------------------------------------------------------
// Prep: convert all fp32 weights to bf16 into workspace.
// Segments (elements): in_proj 98304 | out 32768 | ff1 131072 | ff2 131072
// --------------------------------------------------------------------------
extern "C" __global__ void prep_weights_bf16(const float* __restrict__ w_in,
                                             const float* __restrict__ w_out,
                                             const float* __restrict__ w_ff1,
                                             const float* __restrict__ w_ff2,
                                             unsigned short* __restrict__ ws) {
    int i = blockIdx.x * 256 + threadIdx.x;     // grid covers exactly 393216
    float v;
    if (i < 98304)       v = w_in[i];
    else if (i < 131072) v = w_out[i - 98304];
    else if (i < 262144) v = w_ff1[i - 131072];
    else                 v = w_ff2[i - 262144];
    ws[i] = f2bf(v);
}

// --------------------------------------------------------------------------
// Main fused kernel. block = 512 threads = 8 waves. grid = 1024 (one per b).
// --------------------------------------------------------------------------
extern "C" __global__ void __launch_bounds__(512)
fused_transformer(const float* __restrict__ x,
                  const float* __restrict__ mask,
                  const float* __restrict__ inp_b,
                  const float* __restrict__ out_b,
                  const float* __restrict__ ln1g, const float* __restrict__ ln1b,
                  const float* __restrict__ ff1b, const float* __restrict__ ff2b,
                  const float* __restrict__ ln2g, const float* __restrict__ ln2b,
                  const unsigned short* __restrict__ w_inp,
                  const unsigned short* __restrict__ w_out,
                  const unsigned short* __restrict__ w_ff1,
                  const unsigned short* __restrict__ w_ff2,
                  float* __restrict__ out) {
    // 152 KiB static LDS (gfx950: 160 KiB addressable per workgroup)
    __shared__ __align__(16) unsigned short xs[128 * XS_S];  // x (bf16), 34 KiB
    __shared__ __align__(16) unsigned short qk[128 * QK_S];  // q|k ; o->q cols, 66 KiB
    __shared__ __align__(16) unsigned short vt[128 * VT_S];  // V^T, reused as FF hidden, 34 KiB
    __shared__ __align__(16) unsigned short ps[8 * 16 * PS_S]; // per-wave P scratch / LN scratch, 18 KiB

    const int tid = threadIdx.x;
    const int w   = tid >> 6;        // wave 0..7
    const int lid = tid & 63;
    const int l15 = lid & 15;
    const int kg  = lid >> 4;        // k-group 0..3
    const int b   = blockIdx.x;

    // LN scratch aliases ps (only live between barriers, never with attention)
    float* part_s = (float*)ps;          // [8][128]
    float* part_q = part_s + 1024;       // [8][128]
    float* mean_s = part_s + 2048;       // [128]
    float* rstd_s = mean_s + 128;        // [128]

    // ---- stage x[b] (fp32 global) -> xs (bf16 LDS), coalesced float4 ----
    const float* xb = x + (size_t)b * 16384;
    #pragma unroll
    for (int i = 0; i < 8; ++i) {
        int e = i * 2048 + tid * 4;
        float4 v4 = *(const float4*)(xb + e);
        int row = e >> 7, col = e & 127;
        ushort4 pk;
        pk.x = f2bf(v4.x); pk.y = f2bf(v4.y); pk.z = f2bf(v4.z); pk.w = f2bf(v4.w);
        *(ushort4*)(xs + row * XS_S + col) = pk;
    }
    // additive key mask, col = nt*16 + l15, kept in registers for all layers
    float mreg[8];
    #pragma unroll
    for (int nt = 0; nt < 8; ++nt) mreg[nt] = mask[b * 128 + nt * 16 + l15];

    __syncthreads();

    for (int l = 0; l < 2; ++l) {
        // ================= Phase A: QKV projection (by-N, 3 n-tiles/wave) ===
        {
            bf16x8 bw[3][4];
            float bias[3];
            #pragma unroll
            for (int i = 0; i < 3; ++i) {
                int nrow = l * 384 + (w + 8 * i) * 16 + l15;   // tile w -> q, w+8 -> k, w+16 -> v
                #pragma unroll
                for (int ks = 0; ks < 4; ++ks)
                    bw[i][ks] = *(const bf16x8*)(w_inp + (size_t)nrow * 128 + ks * 32 + kg * 8);
                bias[i] = inp_b[nrow];
            }
            for (int mt = 0; mt < 8; ++mt) {
                bf16x8 ax[4];
                #pragma unroll
                for (int ks = 0; ks < 4; ++ks)
                    ax[ks] = *(const bf16x8*)(xs + (mt * 16 + l15) * XS_S + ks * 32 + kg * 8);
                #pragma unroll
                for (int i = 0; i < 3; ++i) {
                    fx4 acc = {bias[i], bias[i], bias[i], bias[i]};
                    #pragma unroll
                    for (int ks = 0; ks < 4; ++ks) acc = MFMA16(ax[ks], bw[i][ks], acc);
                    if (i < 2) {                       // q (cols 0..127) / k (cols 128..255)
                        int colb = i * 128 + w * 16 + l15;
                        #pragma unroll
                        for (int r = 0; r < 4; ++r)
                            qk[(mt * 16 + kg * 4 + r) * QK_S + colb] = f2bf(acc[r]);
                    } else {                           // v -> transposed store vT[d][t]
                        ushort4 pk;
                        pk.x = f2bf(acc[0]); pk.y = f2bf(acc[1]);
                        pk.z = f2bf(acc[2]); pk.w = f2bf(acc[3]);
                        *(ushort4*)(vt + (w * 16 + l15) * VT_S + mt * 16 + kg * 4) = pk;
                    }
                }
            }
        }
        __syncthreads();

        // ================= Phase B: attention, wave w == head h =============
        {
            const int h = w;
            unsigned short* psw = ps + w * 16 * PS_S;
            for (int mt = 0; mt < 8; ++mt) {
                // scores S[16 x 128] via K=32 MFMA with k=16..31 zero-padded
                bf16x8 aq = {};
                if (kg < 2) aq = *(const bf16x8*)(qk + (mt * 16 + l15) * QK_S + h * 16 + kg * 8);
                fx4 sc[8];
                #pragma unroll
                for (int nt = 0; nt < 8; ++nt) {
                    bf16x8 bk = {};
                    if (kg < 2) bk = *(const bf16x8*)(qk + (nt * 16 + l15) * QK_S + 128 + h * 16 + kg * 8);
                    fx4 z = {0.f, 0.f, 0.f, 0.f};
                    sc[nt] = MFMA16(aq, bk, z);
                }
                // scale + mask + row softmax (row = (kg,reg); cols = 16 lanes x 8 frags)
                float mx[4], sm[4];
                #pragma unroll
                for (int r = 0; r < 4; ++r) mx[r] = -3.0e38f;
                #pragma unroll
                for (int nt = 0; nt < 8; ++nt)
                    #pragma unroll
                    for (int r = 0; r < 4; ++r) {
                        float v = sc[nt][r] * 0.25f + mreg[nt];
                        sc[nt][r] = v;
                        mx[r] = fmaxf(mx[r], v);
                    }
                #pragma unroll
                for (int s = 1; s < 16; s <<= 1)
                    #pragma unroll
                    for (int r = 0; r < 4; ++r) mx[r] = fmaxf(mx[r], __shfl_xor(mx[r], s, 64));
                #pragma unroll
                for (int r = 0; r < 4; ++r) sm[r] = 0.f;
                #pragma unroll
                for (int nt = 0; nt < 8; ++nt)
                    #pragma unroll
                    for (int r = 0; r < 4; ++r) {
                        float e = __expf(sc[nt][r] - mx[r]);
                        sc[nt][r] = e;
                        sm[r] += e;
                    }
                #pragma unroll
                for (int s = 1; s < 16; s <<= 1)
                    #pragma unroll
                    for (int r = 0; r < 4; ++r) sm[r] += __shfl_xor(sm[r], s, 64);
                float inv[4];
                #pragma unroll
                for (int r = 0; r < 4; ++r) inv[r] = 1.f / sm[r];

                // P -> LDS (C-layout -> A-layout) in two 64-col chunks, then PV
                fx4 oacc = {0.f, 0.f, 0.f, 0.f};
                #pragma unroll
                for (int ch = 0; ch < 2; ++ch) {
                    #pragma unroll
                    for (int f = 0; f < 4; ++f) {
                        int nt = ch * 4 + f;
                        #pragma unroll
                        for (int r = 0; r < 4; ++r)
                            psw[(kg * 4 + r) * PS_S + nt * 16 + l15 - ch * 64] =
                                f2bf(sc[nt][r] * inv[r]);
                    }
                    asm volatile("s_waitcnt lgkmcnt(0)" ::: "memory");  // own-wave write->read
                    #pragma unroll
                    for (int ks = 0; ks < 2; ++ks) {
                        bf16x8 ap = *(const bf16x8*)(psw + l15 * PS_S + ks * 32 + kg * 8);
                        bf16x8 bv = *(const bf16x8*)(vt + (h * 16 + l15) * VT_S + ch * 64 + ks * 32 + kg * 8);
                        oacc = MFMA16(ap, bv, oacc);
                    }
                }
                // o_h overwrites q_h columns (safe: q rows of this m-tile consumed)
                #pragma unroll
                for (int r = 0; r < 4; ++r)
                    qk[(mt * 16 + kg * 4 + r) * QK_S + h * 16 + l15] = f2bf(oacc[r]);
            }
        }
        __syncthreads();

        // ========= Phase C: out-proj + bias + residual + LayerNorm1 =========
        {
            const int col = w * 16 + l15;          // fixed per lane (by-N)
            bf16x8 bw[4];
            #pragma unroll
            for (int ks = 0; ks < 4; ++ks)
                bw[ks] = *(const bf16x8*)(w_out + (size_t)(l * 128 + col) * 128 + ks * 32 + kg * 8);
            fx4 acc[8];
            for (int mt = 0; mt < 8; ++mt) {
                fx4 a = {0.f, 0.f, 0.f, 0.f};
                #pragma unroll
                for (int ks = 0; ks < 4; ++ks) {
                    bf16x8 af = *(const bf16x8*)(qk + (mt * 16 + l15) * QK_S + ks * 32 + kg * 8);
                    a = MFMA16(af, bw[ks], a);
                }
                acc[mt] = a;
            }
            float ob = out_b[l * 128 + col];
            #pragma unroll
            for (int mt = 0; mt < 8; ++mt)
                #pragma unroll
                for (int r = 0; r < 4; ++r)
                    acc[mt][r] += ob + bf2f(xs[(mt * 16 + kg * 4 + r) * XS_S + col]);
            // per-wave partial row sums (16 cols) -> LDS, combine by 128 threads
            #pragma unroll
            for (int mt = 0; mt < 8; ++mt) {
                fx4 s = acc[mt], q;
                #pragma unroll
                for (int r = 0; r < 4; ++r) q[r] = s[r] * s[r];
                #pragma unroll
                for (int st = 1; st < 16; st <<= 1)
                    #pragma unroll
                    for (int r = 0; r < 4; ++r) {
                        s[r] += __shfl_xor(s[r], st, 64);
                        q[r] += __shfl_xor(q[r], st, 64);
                    }
                if (l15 == 0) {
                    *(fx4*)(part_s + w * 128 + mt * 16 + kg * 4) = s;
                    *(fx4*)(part_q + w * 128 + mt * 16 + kg * 4) = q;
                }
            }
            __syncthreads();
            if (tid < 128) {
                float ms = 0.f, mq = 0.f;
                #pragma unroll
                for (int wv = 0; wv < 8; ++wv) {
                    ms += part_s[wv * 128 + tid];
                    mq += part_q[wv * 128 + tid];
                }
                float mean = ms * 0.0078125f;
                float var  = mq * 0.0078125f - mean * mean;
                mean_s[tid] = mean;
                rstd_s[tid] = rsqrtf(var + 1e-5f);
            }
            __syncthreads();
            float g = ln1g[l * 128 + col], bb = ln1b[l * 128 + col];
            #pragma unroll
            for (int mt = 0; mt < 8; ++mt)
                #pragma unroll
                for (int r = 0; r < 4; ++r) {
                    int row = mt * 16 + kg * 4 + r;
                    float v = (acc[mt][r] - mean_s[row]) * rstd_s[row] * g + bb;
                    xs[row * XS_S + col] = f2bf(v);
                }
        }
        __syncthreads();

        // ======== Phase D: FF, 4 K-chunks of 128; hidden staged in vt =======
        fx4 yacc[8];
        {
            fx4 zz = {0.f, 0.f, 0.f, 0.f};
            #pragma unroll
            for (int mt = 0; mt < 8; ++mt) yacc[mt] = zz;
        }
        for (int c = 0; c < 4; ++c) {
            {   // FF1 chunk + bias + relu -> vt (by-N)
                const int nrow = l * 512 + c * 128 + w * 16 + l15;
                bf16x8 b1[4];
                #pragma unroll
                for (int ks = 0; ks < 4; ++ks)
                    b1[ks] = *(const bf16x8*)(w_ff1 + (size_t)nrow * 128 + ks * 32 + kg * 8);
                float f1 = ff1b[nrow];
                for (int mt = 0; mt < 8; ++mt) {
                    fx4 a = {f1, f1, f1, f1};
                    #pragma unroll
                    for (int ks = 0; ks < 4; ++ks) {
                        bf16x8 ax = *(const bf16x8*)(xs + (mt * 16 + l15) * XS_S + ks * 32 + kg * 8);
                        a = MFMA16(ax, b1[ks], a);
                    }
                    #pragma unroll
                    for (int r = 0; r < 4; ++r)
                        vt[(mt * 16 + kg * 4 + r) * VT_S + w * 16 + l15] = f2bf(fmaxf(a[r], 0.f));
                }
            }
            __syncthreads();
            {   // FF2 partial accumulate (by-N), yacc held across chunks
                bf16x8 b2[4];
                #pragma unroll
                for (int ks = 0; ks < 4; ++ks)
                    b2[ks] = *(const bf16x8*)(w_ff2 + (size_t)(l * 128 + w * 16 + l15) * 512
                                              + c * 128 + ks * 32 + kg * 8);
                for (int mt = 0; mt < 8; ++mt) {
                    #pragma unroll
                    for (int ks = 0; ks < 4; ++ks) {
                        bf16x8 ah = *(const bf16x8*)(vt + (mt * 16 + l15) * VT_S + ks * 32 + kg * 8);
                        yacc[mt] = MFMA16(ah, b2[ks], yacc[mt]);
                    }
                }
            }
            __syncthreads();
        }

        // ========= Phase E: + bias + residual + LayerNorm2 (+ output) =======
        {
            const int col = w * 16 + l15;
            float fb = ff2b[l * 128 + col];
            #pragma unroll
            for (int mt = 0; mt < 8; ++mt)
                #pragma unroll
                for (int r = 0; r < 4; ++r)
                    yacc[mt][r] += fb + bf2f(xs[(mt * 16 + kg * 4 + r) * XS_S + col]);
            #pragma unroll
            for (int mt = 0; mt < 8; ++mt) {
                fx4 s = yacc[mt], q;
                #pragma unroll
                for (int r = 0; r < 4; ++r) q[r] = s[r] * s[r];
                #pragma unroll
                for (int st = 1; st < 16; st <<= 1)
                    #pragma unroll
                    for (int r = 0; r < 4; ++r) {
                        s[r] += __shfl_xor(s[r], st, 64);
                        q[r] += __shfl_xor(q[r], st, 64);
                    }
                if (l15 == 0) {
                    *(fx4*)(part_s + w * 128 + mt * 16 + kg * 4) = s;
                    *(fx4*)(part_q + w * 128 + mt * 16 + kg * 4) = q;
                }
            }
            __syncthreads();
            if (tid < 128) {
                float ms = 0.f, mq = 0.f;
                #pragma unroll
                for (int wv = 0; wv < 8; ++wv) {
                    ms += part_s[wv * 128 + tid];
                    mq += part_q[wv * 128 + tid];
                }
                float mean = ms * 0.0078125f;
                float var  = mq * 0.0078125f - mean * mean;
                mean_s[tid] = mean;
                rstd_s[tid] = rsqrtf(var + 1e-5f);
            }
            __syncthreads();
            float g = ln2g[l * 128 + col], bb = ln2b[l * 128 + col];
            if (l == 1) {   // final layer: write fp32 output directly (pre-rounding)
                float* ob = out + (size_t)b * 16384;
                #pragma unroll
                for (int mt = 0; mt < 8; ++mt)
                    #pragma unroll
                    for (int r = 0; r < 4; ++r) {
                        int row = mt * 16 + kg * 4 + r;
                        ob[row * 128 + col] = (yacc[mt][r] - mean_s[row]) * rstd_s[row] * g + bb;
                    }
            } else {
                #pragma unroll
                for (int mt = 0; mt < 8; ++mt)
                    #pragma unroll
                    for (int r = 0; r < 4; ++r) {
                        int row = mt * 16 + kg * 4 + r;
                        float v = (yacc[mt][r] - mean_s[row]) * rstd_s[row] * g + bb;
                        xs[row * XS_S + col] = f2bf(v);
                    }
            }
        }
        __syncthreads();
    }
}

// --------------------------------------------------------------------------
extern "C" void kernel_launch(void* const* d_in, const int* in_sizes, int n_in,
                              void* d_out, int out_size, void* d_ws, size_t ws_size,
                              hipStream_t stream) {
    const float* x    = (const float*)d_in[0];
    const float* mask = (const float*)d_in[1];
    const float* w_in = (const float*)d_in[2];
    const float* b_in = (const float*)d_in[3];
    const float* w_o  = (const float*)d_in[4];
    const float* b_o  = (const float*)d_in[5];
    const float* g1   = (const float*)d_in[6];
    const float* bb1  = (const float*)d_in[7];
    const float* w1   = (const float*)d_in[8];
    const float* b1   = (const float*)d_in[9];
    const float* w2   = (const float*)d_in[10];
    const float* b2   = (const float*)d_in[11];
    const float* g2   = (const float*)d_in[12];
    const float* bb2  = (const float*)d_in[13];

    unsigned short* ws = (unsigned short*)d_ws;   // bf16 weights, 786432 B
    prep_weights_bf16<<<1536, 256, 0, stream>>>(w_in, w_o, w1, w2, ws);
    fused_transformer<<<1024, 512, 0, stream>>>(
        x, mask, b_in, b_o, g1, bb1, b1, b2, g2, bb2,
        ws,                 // in_proj  [L][384][128]
        ws + 98304,         // out_w    [L][128][128]
        ws + 131072,        // ff1_w    [L][512][128]
        ws + 262144,        // ff2_w    [L][128][512]
        (float*)d_out);
}